// Round 1
// baseline (97.609 us; speedup 1.0000x reference)
//
#include <hip/hip_runtime.h>
#include <math.h>

// Problem constants (mirrors reference)
#define BATCH    1024
#define NLM      13
#define GRID_HW  256
// ELL_W=1, GAU_W=1, REG_W=0.3, VIS_W=0.01
// SIG_MAJ=0.15 SIG_MIN=0.05 ELL_RADIUS=0.3
// SIGMA=0.1 GAU_RADIUS=0.2 SHARP=1.0 EPS=1e-8

// Kernel 1: per-batch grid sums over the bounding box of the r<=0.3 disc.
// One block (256 threads) per batch. Writes per_batch[b] =
// e_per + g_per if visible else 0. Deterministic (no atomics).
__global__ __launch_bounds__(256) void grid_loss_kernel(
    const float* __restrict__ pred_lm,   // (B,13,2)
    const float* __restrict__ tgt_lm,    // (B,13,2)
    const float* __restrict__ tgt_vis,   // (B,13)
    float* __restrict__ per_batch)       // (B) in d_ws
{
    const int b = blockIdx.x;
    const float vis = tgt_vis[b * NLM];

    // visible = (vis >= 0.5): whole batch contributes 0 otherwise — skip.
    if (vis < 0.5f) {
        if (threadIdx.x == 0) per_batch[b] = 0.0f;
        return;
    }

    const float btx = tgt_lm[b * (NLM * 2) + 0];
    const float bty = tgt_lm[b * (NLM * 2) + 1];
    const float bpx = pred_lm[b * (NLM * 2) + 0];
    const float bpy = pred_lm[b * (NLM * 2) + 1];

    // Conservative pixel bounding box covering dt <= 0.3 (grid step = 1/255).
    const float R = 0.3f;
    int c0 = max(0, (int)floorf((btx - R) * 255.0f));
    int c1 = min(GRID_HW - 1, (int)ceilf((btx + R) * 255.0f));
    int r0 = max(0, (int)floorf((bty - R) * 255.0f));
    int r1 = min(GRID_HW - 1, (int)ceilf((bty + R) * 255.0f));
    const int ncols = c1 - c0 + 1;
    const int total = (r1 - r0 + 1) * ncols;

    const float inv255   = 1.0f / 255.0f;
    const float gau_r2   = 0.2f * 0.2f;            // GAU_RADIUS^2
    const float ell_r2   = 0.3f * 0.3f;            // ELL_RADIUS^2
    const float inv_2gs2 = 1.0f / (2.0f * 0.01f);  // 1/(2*(SIGMA/SHARP)^2) = 50
    const float inv_maj2 = 1.0f / (0.15f * 0.15f);
    const float inv_min2 = 1.0f / (0.05f * 0.05f);

    float gw_sum = 0.0f, gwdp_sum = 0.0f, ew_sum = 0.0f, ewdp_sum = 0.0f;

    for (int i = threadIdx.x; i < total; i += 256) {
        int rr = i / ncols;
        int cc = i - rr * ncols;
        float x = (float)(c0 + cc) * inv255;
        float y = (float)(r0 + rr) * inv255;
        float dxt = x - btx;
        float dyt = y - bty;
        float dt2 = dxt * dxt + dyt * dyt;
        if (dt2 > ell_r2) continue;                 // outside both masks
        float dxp = x - bpx;
        float dyp = y - bpy;
        float dp  = sqrtf(dxp * dxp + dyp * dyp);
        float ed  = dxt * dxt * inv_maj2 + dyt * dyt * inv_min2;
        float ew  = __expf(-0.5f * ed);
        ew_sum   += ew;
        ewdp_sum += ew * dp;
        if (dt2 <= gau_r2) {
            float gw  = __expf(-dt2 * inv_2gs2);
            gw_sum   += gw;
            gwdp_sum += gw * dp;
        }
    }

    // Block reduction: wave64 shuffle tree, then LDS across the 4 waves.
    __shared__ float sdata[4][4];
    const int lane = threadIdx.x & 63;
    const int wave = threadIdx.x >> 6;
    #pragma unroll
    for (int off = 32; off > 0; off >>= 1) {
        gw_sum   += __shfl_down(gw_sum,   off);
        gwdp_sum += __shfl_down(gwdp_sum, off);
        ew_sum   += __shfl_down(ew_sum,   off);
        ewdp_sum += __shfl_down(ewdp_sum, off);
    }
    if (lane == 0) {
        sdata[0][wave] = gw_sum;
        sdata[1][wave] = gwdp_sum;
        sdata[2][wave] = ew_sum;
        sdata[3][wave] = ewdp_sum;
    }
    __syncthreads();
    if (threadIdx.x == 0) {
        float g = 0.0f, gd = 0.0f, e = 0.0f, ed2 = 0.0f;
        #pragma unroll
        for (int w = 0; w < 4; ++w) {
            g   += sdata[0][w];
            gd  += sdata[1][w];
            e   += sdata[2][w];
            ed2 += sdata[3][w];
        }
        const float EPSf = 1e-8f;
        // ELL_W * e_per + GAU_W * g_per, both weights 1.0
        per_batch[b] = ed2 / (e + EPSf) + gd / (g + EPSf);
    }
}

// Kernel 2: single block — reduce per-batch contribs, add regression + BCE.
__global__ __launch_bounds__(256) void finalize_kernel(
    const float* __restrict__ per_batch,
    const float* __restrict__ pred_lm,
    const float* __restrict__ tgt_lm,
    const float* __restrict__ pred_vis,
    const float* __restrict__ tgt_vis,
    float* __restrict__ out)
{
    float s_grid = 0.0f, s_reg = 0.0f, s_vis = 0.0f;

    for (int b = threadIdx.x; b < BATCH; b += 256) {
        s_grid += per_batch[b];

        #pragma unroll
        for (int k = 0; k < 2; ++k) {
            float ad = fabsf(pred_lm[b * (NLM * 2) + k] - tgt_lm[b * (NLM * 2) + k]);
            s_reg += (ad < 1.0f) ? (0.5f * ad * ad) : (ad - 0.5f);
        }

        float p = fminf(fmaxf(pred_vis[b * NLM], 1e-7f), 1.0f - 1e-7f);
        float t = tgt_vis[b * NLM];
        s_vis += -(t * __logf(p) + (1.0f - t) * __logf(1.0f - p));
    }

    __shared__ float sdata[3][4];
    const int lane = threadIdx.x & 63;
    const int wave = threadIdx.x >> 6;
    #pragma unroll
    for (int off = 32; off > 0; off >>= 1) {
        s_grid += __shfl_down(s_grid, off);
        s_reg  += __shfl_down(s_reg,  off);
        s_vis  += __shfl_down(s_vis,  off);
    }
    if (lane == 0) {
        sdata[0][wave] = s_grid;
        sdata[1][wave] = s_reg;
        sdata[2][wave] = s_vis;
    }
    __syncthreads();
    if (threadIdx.x == 0) {
        float g = 0.0f, r = 0.0f, v = 0.0f;
        #pragma unroll
        for (int w = 0; w < 4; ++w) {
            g += sdata[0][w];
            r += sdata[1][w];
            v += sdata[2][w];
        }
        const float EPSf = 1e-8f;
        float heat = g / ((float)BATCH + EPSf);          // ELL_W + GAU_W terms
        float reg  = r / (float)(BATCH * 2);             // mean over (B,2)
        float visl = v / (float)BATCH;                   // mean over (B,1)
        out[0] = heat + 0.3f * reg + 0.01f * visl;
    }
}

extern "C" void kernel_launch(void* const* d_in, const int* in_sizes, int n_in,
                              void* d_out, int out_size, void* d_ws, size_t ws_size,
                              hipStream_t stream) {
    const float* pred_lm  = (const float*)d_in[0];  // (1024,13,2)
    const float* tgt_lm   = (const float*)d_in[1];  // (1024,13,2)
    const float* pred_vis = (const float*)d_in[2];  // (1024,13)
    const float* tgt_vis  = (const float*)d_in[3];  // (1024,13)
    float* out = (float*)d_out;
    float* per_batch = (float*)d_ws;                // 1024 floats of scratch

    grid_loss_kernel<<<BATCH, 256, 0, stream>>>(pred_lm, tgt_lm, tgt_vis, per_batch);
    finalize_kernel<<<1, 256, 0, stream>>>(per_batch, pred_lm, tgt_lm,
                                           pred_vis, tgt_vis, out);
}

// Round 2
// 84.128 us; speedup vs baseline: 1.1602x; 1.1602x over previous
//
#include <hip/hip_runtime.h>
#include <math.h>

// Problem constants (mirrors reference)
#define BATCH    1024
#define NLM      13
#define GRID_HW  256
// ELL_W=1, GAU_W=1, REG_W=0.3, VIS_W=0.01
// SIG_MAJ=0.15 SIG_MIN=0.05 ELL_RADIUS=0.3
// SIGMA=0.1 GAU_RADIUS=0.2 SHARP=1.0 EPS=1e-8
//
// Structure: kernel 1 = 2 blocks per batch (grid 2048), 256 threads as a
// 16x16 tile walking the r<=0.3 bounding box. No integer div, no LDS, no
// inner-loop branches. Per-wave partial sums (float4: gw, gwdp, ew, ewdp)
// written to d_ws at [batch][half][wave] — deterministic. Kernel 2 reduces
// the 8 float4 per batch, forms the two ratios, and adds regression + BCE.

#define HALVES 2   // row-slab split of each batch across 2 blocks

__global__ __launch_bounds__(256) void grid_loss_kernel(
    const float* __restrict__ pred_lm,   // (B,13,2)
    const float* __restrict__ tgt_lm,    // (B,13,2)
    const float* __restrict__ tgt_vis,   // (B,13)
    float4* __restrict__ partials)       // (B, HALVES, 4 waves) in d_ws
{
    const int blk  = blockIdx.x;
    const int b    = blk >> 1;           // batch
    const int h    = blk & 1;            // row-slab half
    const int lane = threadIdx.x & 63;
    const int wave = threadIdx.x >> 6;
    const int tx   = threadIdx.x & 15;   // 16x16 tile coords
    const int ty   = threadIdx.x >> 4;

    const float vis = tgt_vis[b * NLM];

    float s_gw = 0.0f, s_gwd = 0.0f, s_ew = 0.0f, s_ewd = 0.0f;

    if (vis >= 0.5f) {
        const float btx = tgt_lm[b * (NLM * 2) + 0];
        const float bty = tgt_lm[b * (NLM * 2) + 1];
        const float bpx = pred_lm[b * (NLM * 2) + 0];
        const float bpy = pred_lm[b * (NLM * 2) + 1];

        // Conservative pixel bbox covering dt <= 0.3 (grid step = 1/255);
        // the dt2 masks below re-check exactly, so conservative is safe.
        const float R = 0.3f;
        const int c0 = max(0, (int)floorf((btx - R) * 255.0f));
        const int c1 = min(GRID_HW - 1, (int)ceilf((btx + R) * 255.0f));
        const int r0 = max(0, (int)floorf((bty - R) * 255.0f));
        const int r1 = min(GRID_HW - 1, (int)ceilf((bty + R) * 255.0f));

        const float inv255 = 1.0f / 255.0f;
        const float du     = 16.0f * inv255;        // x stride of the tile
        const float cMaj   = -0.5f / (0.15f * 0.15f);  // ellipsoid x coeff
        const float cMin   = -0.5f / (0.05f * 0.05f);  // ellipsoid y coeff
        const float cGau   = -50.0f;                   // -1/(2*sigma^2)
        const float ell_r2 = 0.09f;
        const float gau_r2 = 0.04f;
        const float dxo    = btx - bpx;             // u -> dxp offset

        const float u0 = (float)(c0 + tx) * inv255 - btx;

        // rows: this block handles slabs h, h+2, h+4, ... (16 rows each)
        for (int ry = r0 + ty + 16 * h; ry <= r1; ry += 16 * HALVES) {
            const float y    = (float)ry * inv255;
            const float v    = y - bty;
            const float v2   = v * v;
            const float dyp  = y - bpy;
            const float dyp2 = dyp * dyp;
            const float eyN  = cMin * v2;           // row term of ell exponent

            float u = u0;
            for (int cx = c0 + tx; cx <= c1; cx += 16, u += du) {
                const float u2  = u * u;
                const float dt2 = u2 + v2;
                const float dxp = u + dxo;
                const float dp  = sqrtf(fmaf(dxp, dxp, dyp2));
                float ew = __expf(fmaf(u2, cMaj, eyN));
                ew = (dt2 <= ell_r2) ? ew : 0.0f;
                float gw = __expf(dt2 * cGau);
                gw = (dt2 <= gau_r2) ? gw : 0.0f;
                s_ew  += ew;
                s_ewd  = fmaf(ew, dp, s_ewd);
                s_gw  += gw;
                s_gwd  = fmaf(gw, dp, s_gwd);
            }
        }
    }

    // Wave-level shuffle reduce; lane 0 of each wave writes its partial.
    #pragma unroll
    for (int off = 32; off > 0; off >>= 1) {
        s_gw  += __shfl_down(s_gw,  off);
        s_gwd += __shfl_down(s_gwd, off);
        s_ew  += __shfl_down(s_ew,  off);
        s_ewd += __shfl_down(s_ewd, off);
    }
    if (lane == 0) {
        partials[(b * HALVES + h) * 4 + wave] =
            make_float4(s_gw, s_gwd, s_ew, s_ewd);
    }
}

// Kernel 2: single block — reduce partials, form ratios, add reg + BCE.
__global__ __launch_bounds__(256) void finalize_kernel(
    const float4* __restrict__ partials, // (B, HALVES, 4)
    const float* __restrict__ pred_lm,
    const float* __restrict__ tgt_lm,
    const float* __restrict__ pred_vis,
    const float* __restrict__ tgt_vis,
    float* __restrict__ out)
{
    float s_grid = 0.0f, s_reg = 0.0f, s_vis = 0.0f;

    for (int b = threadIdx.x; b < BATCH; b += 256) {
        float gw = 0.0f, gwd = 0.0f, ew = 0.0f, ewd = 0.0f;
        #pragma unroll
        for (int j = 0; j < HALVES * 4; ++j) {
            float4 p = partials[b * (HALVES * 4) + j];
            gw += p.x; gwd += p.y; ew += p.z; ewd += p.w;
        }
        const float EPSf = 1e-8f;
        s_grid += ewd / (ew + EPSf) + gwd / (gw + EPSf);

        #pragma unroll
        for (int k = 0; k < 2; ++k) {
            float ad = fabsf(pred_lm[b * (NLM * 2) + k] - tgt_lm[b * (NLM * 2) + k]);
            s_reg += (ad < 1.0f) ? (0.5f * ad * ad) : (ad - 0.5f);
        }

        float p = fminf(fmaxf(pred_vis[b * NLM], 1e-7f), 1.0f - 1e-7f);
        float t = tgt_vis[b * NLM];
        s_vis += -(t * __logf(p) + (1.0f - t) * __logf(1.0f - p));
    }

    __shared__ float sdata[3][4];
    const int lane = threadIdx.x & 63;
    const int wave = threadIdx.x >> 6;
    #pragma unroll
    for (int off = 32; off > 0; off >>= 1) {
        s_grid += __shfl_down(s_grid, off);
        s_reg  += __shfl_down(s_reg,  off);
        s_vis  += __shfl_down(s_vis,  off);
    }
    if (lane == 0) {
        sdata[0][wave] = s_grid;
        sdata[1][wave] = s_reg;
        sdata[2][wave] = s_vis;
    }
    __syncthreads();
    if (threadIdx.x == 0) {
        float g = 0.0f, r = 0.0f, v = 0.0f;
        #pragma unroll
        for (int w = 0; w < 4; ++w) {
            g += sdata[0][w];
            r += sdata[1][w];
            v += sdata[2][w];
        }
        const float EPSf = 1e-8f;
        float heat = g / ((float)BATCH + EPSf);   // ELL_W + GAU_W terms
        float reg  = r / (float)(BATCH * 2);      // mean over (B,2)
        float visl = v / (float)BATCH;            // mean over (B,1)
        out[0] = heat + 0.3f * reg + 0.01f * visl;
    }
}

extern "C" void kernel_launch(void* const* d_in, const int* in_sizes, int n_in,
                              void* d_out, int out_size, void* d_ws, size_t ws_size,
                              hipStream_t stream) {
    const float* pred_lm  = (const float*)d_in[0];  // (1024,13,2)
    const float* tgt_lm   = (const float*)d_in[1];  // (1024,13,2)
    const float* pred_vis = (const float*)d_in[2];  // (1024,13)
    const float* tgt_vis  = (const float*)d_in[3];  // (1024,13)
    float* out = (float*)d_out;
    float4* partials = (float4*)d_ws;               // 1024*2*4 float4 = 128 KB

    grid_loss_kernel<<<BATCH * HALVES, 256, 0, stream>>>(
        pred_lm, tgt_lm, tgt_vis, partials);
    finalize_kernel<<<1, 256, 0, stream>>>(partials, pred_lm, tgt_lm,
                                           pred_vis, tgt_vis, out);
}

// Round 3
// 77.845 us; speedup vs baseline: 1.2539x; 1.0807x over previous
//
#include <hip/hip_runtime.h>
#include <math.h>

// Problem constants (mirrors reference)
#define BATCH    1024
#define NLM      13
#define GRID_HW  256
// ELL_W=1, GAU_W=1, REG_W=0.3, VIS_W=0.01
// SIG_MAJ=0.15 SIG_MIN=0.05 ELL_RADIUS=0.3
// SIGMA=0.1 GAU_RADIUS=0.2 SHARP=1.0 EPS=1e-8
//
// k1: 2 blocks/batch (grid 2048), 16x16 tile over the r<=0.3 bbox.
// Separable exponentials: per-thread column terms (u^2, exp(cMaj u^2),
// exp(cGau u^2), dxp^2) precomputed once; row terms hoisted; fixed 10-wide
// fully-unrolled masked inner loop (max bbox width 155 -> ceil(155/16)=10).
// Also computes per-batch smooth-L1 + BCE (one thread per batch) into aux.
// k2: 1024 threads, 1 batch/thread — combine partials, ratios, final scalar.

#define HALVES 2
#define KCOLS  10

__global__ __launch_bounds__(256) void grid_loss_kernel(
    const float* __restrict__ pred_lm,   // (B,13,2)
    const float* __restrict__ tgt_lm,    // (B,13,2)
    const float* __restrict__ pred_vis,  // (B,13)
    const float* __restrict__ tgt_vis,   // (B,13)
    float4* __restrict__ partials,       // (B, HALVES, 4 waves)
    float*  __restrict__ aux)            // (B): 0.3*reg_b/2048 + 0.01*bce_b/1024
{
    const int blk  = blockIdx.x;
    const int b    = blk >> 1;
    const int h    = blk & 1;
    const int lane = threadIdx.x & 63;
    const int wave = threadIdx.x >> 6;
    const int tx   = threadIdx.x & 15;
    const int ty   = threadIdx.x >> 4;

    const float btx = tgt_lm[b * (NLM * 2) + 0];
    const float bty = tgt_lm[b * (NLM * 2) + 1];
    const float bpx = pred_lm[b * (NLM * 2) + 0];
    const float bpy = pred_lm[b * (NLM * 2) + 1];
    const float vis = tgt_vis[b * NLM];

    // Per-batch regression + BCE (independent of visibility), one thread.
    if (h == 0 && threadIdx.x == 0) {
        float adx = fabsf(bpx - btx);
        float ady = fabsf(bpy - bty);
        float rx = (adx < 1.0f) ? (0.5f * adx * adx) : (adx - 0.5f);
        float ry2 = (ady < 1.0f) ? (0.5f * ady * ady) : (ady - 0.5f);
        float p = fminf(fmaxf(pred_vis[b * NLM], 1e-7f), 1.0f - 1e-7f);
        float t = vis;
        float bce = -(t * __logf(p) + (1.0f - t) * __logf(1.0f - p));
        aux[b] = 0.3f * (rx + ry2) * (1.0f / 2048.0f)
               + 0.01f * bce * (1.0f / 1024.0f);
    }

    float s_gw = 0.0f, s_gwd = 0.0f, s_ew = 0.0f, s_ewd = 0.0f;

    if (vis >= 0.5f) {
        const float R = 0.3f;
        const int c0 = max(0, (int)floorf((btx - R) * 255.0f));
        const int c1 = min(GRID_HW - 1, (int)ceilf((btx + R) * 255.0f));
        const int r0 = max(0, (int)floorf((bty - R) * 255.0f));
        const int r1 = min(GRID_HW - 1, (int)ceilf((bty + R) * 255.0f));

        const float inv255 = 1.0f / 255.0f;
        const float du     = 16.0f * inv255;
        const float cMaj   = -0.5f / (0.15f * 0.15f);
        const float cMin   = -0.5f / (0.05f * 0.05f);
        const float cGau   = -50.0f;
        const float ell_r2 = 0.09f;
        const float gau_r2 = 0.04f;
        const float dxo    = btx - bpx;
        const float u0     = (float)(c0 + tx) * inv255 - btx;

        // Per-thread column terms (constant across rows).
        float u2a[KCOLS], emx[KCOLS], egx[KCOLS], dxp2[KCOLS];
        #pragma unroll
        for (int k = 0; k < KCOLS; ++k) {
            float u  = u0 + (float)k * du;
            bool ok  = (c0 + tx + 16 * k) <= c1;  // beyond c1 => dt > R exactly
            float u2 = u * u;
            u2a[k]  = u2;
            emx[k]  = ok ? __expf(cMaj * u2) : 0.0f;
            egx[k]  = ok ? __expf(cGau * u2) : 0.0f;
            float dxp = u + dxo;
            dxp2[k] = dxp * dxp;
        }

        for (int ry = r0 + ty + 16 * h; ry <= r1; ry += 16 * HALVES) {
            const float y    = (float)ry * inv255;
            const float v    = y - bty;
            const float v2   = v * v;
            const float dyp  = y - bpy;
            const float dyp2 = dyp * dyp;
            const float eyE  = __expf(cMin * v2);  // row factor, ellipsoid
            const float gyE  = __expf(cGau * v2);  // row factor, gaussian

            #pragma unroll
            for (int k = 0; k < KCOLS; ++k) {
                float dt2 = u2a[k] + v2;
                float dp  = sqrtf(dxp2[k] + dyp2);
                float ew  = (dt2 <= ell_r2) ? emx[k] * eyE : 0.0f;
                float gw  = (dt2 <= gau_r2) ? egx[k] * gyE : 0.0f;
                s_ew  += ew;
                s_ewd  = fmaf(ew, dp, s_ewd);
                s_gw  += gw;
                s_gwd  = fmaf(gw, dp, s_gwd);
            }
        }
    }

    #pragma unroll
    for (int off = 32; off > 0; off >>= 1) {
        s_gw  += __shfl_down(s_gw,  off);
        s_gwd += __shfl_down(s_gwd, off);
        s_ew  += __shfl_down(s_ew,  off);
        s_ewd += __shfl_down(s_ewd, off);
    }
    if (lane == 0) {
        partials[(b * HALVES + h) * 4 + wave] =
            make_float4(s_gw, s_gwd, s_ew, s_ewd);
    }
}

// k2: 1024 threads, one batch each. No logs (moved to k1).
__global__ __launch_bounds__(1024) void finalize_kernel(
    const float4* __restrict__ partials, // (B, HALVES, 4)
    const float*  __restrict__ aux,      // (B)
    float* __restrict__ out)
{
    const int b = threadIdx.x;
    float gw = 0.0f, gwd = 0.0f, ew = 0.0f, ewd = 0.0f;
    #pragma unroll
    for (int j = 0; j < HALVES * 4; ++j) {
        float4 p = partials[b * (HALVES * 4) + j];
        gw += p.x; gwd += p.y; ew += p.z; ewd += p.w;
    }
    const float EPSf = 1e-8f;
    float t = (ewd / (ew + EPSf) + gwd / (gw + EPSf)) * (1.0f / 1024.0f)
            + aux[b];

    const int lane = threadIdx.x & 63;
    const int wave = threadIdx.x >> 6;
    #pragma unroll
    for (int off = 32; off > 0; off >>= 1) t += __shfl_down(t, off);

    __shared__ float sd[16];
    if (lane == 0) sd[wave] = t;
    __syncthreads();
    if (wave == 0) {
        float v = (lane < 16) ? sd[lane] : 0.0f;
        #pragma unroll
        for (int off = 8; off > 0; off >>= 1) v += __shfl_down(v, off);
        if (lane == 0) out[0] = v;
    }
}

extern "C" void kernel_launch(void* const* d_in, const int* in_sizes, int n_in,
                              void* d_out, int out_size, void* d_ws, size_t ws_size,
                              hipStream_t stream) {
    const float* pred_lm  = (const float*)d_in[0];  // (1024,13,2)
    const float* tgt_lm   = (const float*)d_in[1];  // (1024,13,2)
    const float* pred_vis = (const float*)d_in[2];  // (1024,13)
    const float* tgt_vis  = (const float*)d_in[3];  // (1024,13)
    float* out = (float*)d_out;

    float4* partials = (float4*)d_ws;                        // 128 KB
    float*  aux      = (float*)d_ws + BATCH * HALVES * 4 * 4; // after partials

    grid_loss_kernel<<<BATCH * HALVES, 256, 0, stream>>>(
        pred_lm, tgt_lm, pred_vis, tgt_vis, partials, aux);
    finalize_kernel<<<1, 1024, 0, stream>>>(partials, aux, out);
}